// Round 2
// baseline (430.231 us; speedup 1.0000x reference)
//
#include <hip/hip_runtime.h>

#define E_DIM 512
#define U_DIM 64
#define T_DIM 8
#define A_DIM 32
#define NB    10
#define BATCH 8192
#define BKT_STRIDE 8192

// ws layout: [0,32) int counts[8]; [256, 256+8*8192*4) bucket lists

__global__ __launch_bounds__(256) void bucket_kernel(
    const int* __restrict__ types, int* __restrict__ cnt, int* __restrict__ bkt)
{
    const int i = blockIdx.x * 256 + threadIdx.x;
    const int ty = types[i];
    const unsigned long long below = (1ull << (threadIdx.x & 63)) - 1;
    #pragma unroll
    for (int t = 0; t < T_DIM; ++t) {
        unsigned long long m = __ballot(ty == t);
        if (ty == t) {
            int lead = __ffsll(m) - 1;
            int base = 0;
            if ((threadIdx.x & 63) == lead)
                base = atomicAdd(&cnt[t], (int)__popcll(m));
            base = __shfl(base, lead, 64);
            bkt[t * BKT_STRIDE + base + (int)__popcll(m & below)] = i;
        }
    }
}

static __device__ __forceinline__ float bcast_lane(float x, int l) {
    return __int_as_float(__builtin_amdgcn_readlane(__float_as_int(x), l));
}

__global__ __launch_bounds__(256) void gatne_main(
    const float* __restrict__ node_embeddings,      // [N, 512]
    const float* __restrict__ node_type_embeddings, // [N, 8, 64]
    const float* __restrict__ trans_weights,        // [8, 64, 512]
    const float* __restrict__ trans_weights_s1,     // [8, 64, 32]
    const float* __restrict__ trans_weights_s2,     // [8, 32]
    const int*   __restrict__ train_inputs,         // [B]
    const int*   __restrict__ counts,               // [8]
    const int*   __restrict__ bkt,                  // [8, 8192]
    const int*   __restrict__ node_neigh,           // [B, 8, 10]
    float*       __restrict__ out)                  // [B, 512]
{
    const int ty    = blockIdx.x;
    const int count = counts[ty];
    if ((int)(blockIdx.y * 4) >= count) return;

    const int tid  = threadIdx.x;
    const int lane = tid & 63;
    const int w    = tid >> 6;

    __shared__ __align__(16) float sW1T[A_DIM * 68];     // [a][u], pad 68 -> conflict-free b128
    __shared__ __align__(16) float sNte[4][T_DIM * 68];  // per-wave, pad 68
    __shared__ __align__(16) float sSc[4][8];
    __shared__ float sW2[A_DIM];
    __shared__ int   sNei[4][80];

    // stage w1 transposed + w2 (once per block)
    for (int k = tid; k < U_DIM * A_DIM; k += 256) {
        const int u = k >> 5, a = k & 31;
        sW1T[a * 68 + u] = trans_weights_s1[ty * (U_DIM * A_DIM) + k];
    }
    if (tid < A_DIM) sW2[tid] = trans_weights_s2[ty * A_DIM + tid];
    __syncthreads();

    const float* Wty = trans_weights + (size_t)ty * (U_DIM * E_DIM);
    const int t8 = lane >> 3;   // this lane's attention t
    const int a0 = lane & 7;    // handles a = a0, a0+8, a0+16, a0+24

    for (int j = blockIdx.y; j * 4 < count; j += gridDim.y) {
        const int  si    = j * 4 + w;
        const bool valid = si < count;
        float agg = 0.f;
        int s = 0, ni = 0;

        if (valid) {
            s  = bkt[ty * BKT_STRIDE + si];
            ni = train_inputs[s];
            {
                const int* np = node_neigh + (size_t)s * (T_DIM * NB);
                sNei[w][lane] = np[lane];
                if (lane < 16) sNei[w][64 + lane] = np[64 + lane];
            }
            // ---- gather: lane = u; nte[t] kept in regs + mirrored to LDS ----
            float acc[T_DIM];
            #pragma unroll
            for (int t = 0; t < T_DIM; ++t) {
                float a = 0.f;
                #pragma unroll
                for (int n = 0; n < NB; ++n) {
                    const int nb = sNei[w][t * NB + n];
                    a += node_type_embeddings[(size_t)nb * (T_DIM * U_DIM) + t * U_DIM + lane];
                }
                acc[t] = a;
                sNte[w][t * 68 + lane] = a;
            }
            // ---- attention: h[t8][a0+8k], all-b128 conflict-free LDS ----
            float h0 = 0.f, h1 = 0.f, h2 = 0.f, h3 = 0.f;
            #pragma unroll
            for (int uq = 0; uq < 16; ++uq) {
                const float4 nv  = *(const float4*)&sNte[w][t8 * 68 + uq * 4];
                const float4 wa  = *(const float4*)&sW1T[(a0     ) * 68 + uq * 4];
                const float4 wb  = *(const float4*)&sW1T[(a0 +  8) * 68 + uq * 4];
                const float4 wc  = *(const float4*)&sW1T[(a0 + 16) * 68 + uq * 4];
                const float4 wd  = *(const float4*)&sW1T[(a0 + 24) * 68 + uq * 4];
                h0 = fmaf(nv.x, wa.x, h0); h0 = fmaf(nv.y, wa.y, h0);
                h0 = fmaf(nv.z, wa.z, h0); h0 = fmaf(nv.w, wa.w, h0);
                h1 = fmaf(nv.x, wb.x, h1); h1 = fmaf(nv.y, wb.y, h1);
                h1 = fmaf(nv.z, wb.z, h1); h1 = fmaf(nv.w, wb.w, h1);
                h2 = fmaf(nv.x, wc.x, h2); h2 = fmaf(nv.y, wc.y, h2);
                h2 = fmaf(nv.z, wc.z, h2); h2 = fmaf(nv.w, wc.w, h2);
                h3 = fmaf(nv.x, wd.x, h3); h3 = fmaf(nv.y, wd.y, h3);
                h3 = fmaf(nv.z, wd.z, h3); h3 = fmaf(nv.w, wd.w, h3);
            }
            float r = tanhf(h0) * sW2[a0]      + tanhf(h1) * sW2[a0 + 8]
                    + tanhf(h2) * sW2[a0 + 16] + tanhf(h3) * sW2[a0 + 24];
            r += __shfl_xor(r, 1, 64);
            r += __shfl_xor(r, 2, 64);
            r += __shfl_xor(r, 4, 64);
            if (a0 == 0) sSc[w][t8] = r;
            // ---- softmax over 8 (redundant per lane, registers) ----
            const float4 sc0 = *(const float4*)&sSc[w][0];
            const float4 sc1 = *(const float4*)&sSc[w][4];
            float mx = fmaxf(fmaxf(fmaxf(sc0.x, sc0.y), fmaxf(sc0.z, sc0.w)),
                             fmaxf(fmaxf(sc1.x, sc1.y), fmaxf(sc1.z, sc1.w)));
            const float e0 = __expf(sc0.x - mx), e1 = __expf(sc0.y - mx);
            const float e2 = __expf(sc0.z - mx), e3 = __expf(sc0.w - mx);
            const float e4 = __expf(sc1.x - mx), e5 = __expf(sc1.y - mx);
            const float e6 = __expf(sc1.z - mx), e7 = __expf(sc1.w - mx);
            const float inv = 1.f / (e0 + e1 + e2 + e3 + e4 + e5 + e6 + e7);
            agg = (e0 * acc[0] + e1 * acc[1] + e2 * acc[2] + e3 * acc[3]
                 + e4 * acc[4] + e5 * acc[5] + e6 * acc[6] + e7 * acc[7]) * inv;
        }

        __syncthreads();   // align waves so their W u-loops overlap (L1 reuse)

        if (valid) {
            // ---- projection: out[s] = ne[ni] + agg @ W[ty]; L2-normalize ----
            float v[8];
            const float4* nr = (const float4*)(node_embeddings + (size_t)ni * E_DIM + lane * 8);
            const float4 nv0 = nr[0], nv1 = nr[1];
            v[0] = nv0.x; v[1] = nv0.y; v[2] = nv0.z; v[3] = nv0.w;
            v[4] = nv1.x; v[5] = nv1.y; v[6] = nv1.z; v[7] = nv1.w;
            const float* Wp = Wty + lane * 8;
            #pragma unroll 8
            for (int u = 0; u < U_DIM; ++u) {
                const float au = bcast_lane(agg, u);
                const float4 w0 = *(const float4*)(Wp + (size_t)u * E_DIM);
                const float4 w1 = *(const float4*)(Wp + (size_t)u * E_DIM + 4);
                v[0] = fmaf(au, w0.x, v[0]); v[1] = fmaf(au, w0.y, v[1]);
                v[2] = fmaf(au, w0.z, v[2]); v[3] = fmaf(au, w0.w, v[3]);
                v[4] = fmaf(au, w1.x, v[4]); v[5] = fmaf(au, w1.y, v[5]);
                v[6] = fmaf(au, w1.z, v[6]); v[7] = fmaf(au, w1.w, v[7]);
            }
            float ss = v[0]*v[0] + v[1]*v[1] + v[2]*v[2] + v[3]*v[3]
                     + v[4]*v[4] + v[5]*v[5] + v[6]*v[6] + v[7]*v[7];
            #pragma unroll
            for (int off = 1; off < 64; off <<= 1)
                ss += __shfl_xor(ss, off, 64);
            const float invn = 1.f / fmaxf(sqrtf(ss), 1e-12f);
            float4 o0, o1;
            o0.x = v[0]*invn; o0.y = v[1]*invn; o0.z = v[2]*invn; o0.w = v[3]*invn;
            o1.x = v[4]*invn; o1.y = v[5]*invn; o1.z = v[6]*invn; o1.w = v[7]*invn;
            float4* op = (float4*)(out + (size_t)s * E_DIM + lane * 8);
            op[0] = o0; op[1] = o1;
        }
    }
}

extern "C" void kernel_launch(void* const* d_in, const int* in_sizes, int n_in,
                              void* d_out, int out_size, void* d_ws, size_t ws_size,
                              hipStream_t stream) {
    const float* node_embeddings      = (const float*)d_in[0];
    const float* node_type_embeddings = (const float*)d_in[1];
    const float* trans_weights        = (const float*)d_in[2];
    const float* trans_weights_s1     = (const float*)d_in[3];
    const float* trans_weights_s2     = (const float*)d_in[4];
    const int*   train_inputs         = (const int*)d_in[5];
    const int*   train_types          = (const int*)d_in[6];
    const int*   node_neigh           = (const int*)d_in[7];
    float* out = (float*)d_out;

    int* cnt = (int*)d_ws;
    int* bkt = (int*)((char*)d_ws + 256);

    hipMemsetAsync(cnt, 0, 32, stream);
    bucket_kernel<<<BATCH / 256, 256, 0, stream>>>(train_types, cnt, bkt);
    gatne_main<<<dim3(T_DIM, 128), 256, 0, stream>>>(
        node_embeddings, node_type_embeddings, trans_weights,
        trans_weights_s1, trans_weights_s2,
        train_inputs, cnt, bkt, node_neigh, out);
}

// Round 3
// 416.945 us; speedup vs baseline: 1.0319x; 1.0319x over previous
//
#include <hip/hip_runtime.h>

#define E_DIM 512
#define U_DIM 64
#define T_DIM 8
#define A_DIM 32
#define NB    10
#define BATCH 8192
#define BKT_STRIDE 8192

// ws layout: [0,32) int counts[8]; [256, 256+8*8192*4) bucket lists

__global__ __launch_bounds__(256) void bucket_kernel(
    const int* __restrict__ types, int* __restrict__ cnt, int* __restrict__ bkt)
{
    const int i = blockIdx.x * 256 + threadIdx.x;
    const int ty = types[i];
    const unsigned long long below = (1ull << (threadIdx.x & 63)) - 1;
    #pragma unroll
    for (int t = 0; t < T_DIM; ++t) {
        unsigned long long m = __ballot(ty == t);
        if (ty == t) {
            int lead = __ffsll(m) - 1;
            int base = 0;
            if ((threadIdx.x & 63) == lead)
                base = atomicAdd(&cnt[t], (int)__popcll(m));
            base = __shfl(base, lead, 64);
            bkt[t * BKT_STRIDE + base + (int)__popcll(m & below)] = i;
        }
    }
}

static __device__ __forceinline__ float bcast_lane(float x, int l) {
    return __int_as_float(__builtin_amdgcn_readlane(__float_as_int(x), l));
}

__global__ __launch_bounds__(256) void gatne_main(
    const float* __restrict__ node_embeddings,      // [N, 512]
    const float* __restrict__ node_type_embeddings, // [N, 8, 64]
    const float* __restrict__ trans_weights,        // [8, 64, 512]
    const float* __restrict__ trans_weights_s1,     // [8, 64, 32]
    const float* __restrict__ trans_weights_s2,     // [8, 32]
    const int*   __restrict__ train_inputs,         // [B]
    const int*   __restrict__ counts,               // [8]
    const int*   __restrict__ bkt,                  // [8, 8192]
    const int*   __restrict__ node_neigh,           // [B, 8, 10]
    float*       __restrict__ out)                  // [B, 512]
{
    const int ty    = blockIdx.x;
    const int count = counts[ty];
    const int tid   = threadIdx.x;
    const int lane  = tid & 63;
    const int w     = tid >> 6;

    __shared__ __align__(16) float sW1T[A_DIM * 68];     // [a][u], pad 68: conflict-free b128
    __shared__ __align__(16) float sNte[4][T_DIM * 68];  // per-wave scratch, pad 68
    __shared__ __align__(16) float sSc[4][8];
    __shared__ float sW2[A_DIM];
    __shared__ int   sNei[4][80];

    // stage w1 transposed + w2 (once per block)
    for (int k = tid; k < U_DIM * A_DIM; k += 256) {
        const int u = k >> 5, a = k & 31;
        sW1T[a * 68 + u] = trans_weights_s1[ty * (U_DIM * A_DIM) + k];
    }
    if (tid < A_DIM) sW2[tid] = trans_weights_s2[ty * A_DIM + tid];
    __syncthreads();   // the only block-wide barrier

    const float* Wty = trans_weights + (size_t)ty * (U_DIM * E_DIM);
    const int t8 = lane >> 3;   // this lane's attention t
    const int a0 = lane & 7;    // handles a = a0, a0+8, a0+16, a0+24

    const int wstride = gridDim.y * 4;
    for (int g = blockIdx.y * 4 + w; g * 4 < count; g += wstride) {
        const int nvalid = min(4, count - g * 4);
        int   sidx[4], nidx[4];
        float agg[4];

        // ---- phase A: per sample, gather nte + attention -> agg (lane = u) ----
        #pragma unroll
        for (int i = 0; i < 4; ++i) {
            agg[i] = 0.f; sidx[i] = 0; nidx[i] = 0;
            if (i >= nvalid) continue;                    // wave-uniform branch
            const int s = bkt[ty * BKT_STRIDE + g * 4 + i];
            sidx[i] = s;
            nidx[i] = train_inputs[s];
            {
                const int* np = node_neigh + (size_t)s * (T_DIM * NB);
                sNei[w][lane] = np[lane];
                if (lane < 16) sNei[w][64 + lane] = np[64 + lane];
            }
            float acc[T_DIM];
            #pragma unroll
            for (int t = 0; t < T_DIM; ++t) {
                float a = 0.f;
                #pragma unroll
                for (int n = 0; n < NB; ++n) {
                    const int nb = sNei[w][t * NB + n];
                    a += node_type_embeddings[(size_t)nb * (T_DIM * U_DIM) + t * U_DIM + lane];
                }
                acc[t] = a;
                sNte[w][t * 68 + lane] = a;
            }
            // attention: h[t8][a0+8k], all-b128 conflict-free LDS
            float h0 = 0.f, h1 = 0.f, h2 = 0.f, h3 = 0.f;
            #pragma unroll
            for (int uq = 0; uq < 16; ++uq) {
                const float4 nv = *(const float4*)&sNte[w][t8 * 68 + uq * 4];
                const float4 wa = *(const float4*)&sW1T[(a0     ) * 68 + uq * 4];
                const float4 wb = *(const float4*)&sW1T[(a0 +  8) * 68 + uq * 4];
                const float4 wc = *(const float4*)&sW1T[(a0 + 16) * 68 + uq * 4];
                const float4 wd = *(const float4*)&sW1T[(a0 + 24) * 68 + uq * 4];
                h0 = fmaf(nv.x, wa.x, h0); h0 = fmaf(nv.y, wa.y, h0);
                h0 = fmaf(nv.z, wa.z, h0); h0 = fmaf(nv.w, wa.w, h0);
                h1 = fmaf(nv.x, wb.x, h1); h1 = fmaf(nv.y, wb.y, h1);
                h1 = fmaf(nv.z, wb.z, h1); h1 = fmaf(nv.w, wb.w, h1);
                h2 = fmaf(nv.x, wc.x, h2); h2 = fmaf(nv.y, wc.y, h2);
                h2 = fmaf(nv.z, wc.z, h2); h2 = fmaf(nv.w, wc.w, h2);
                h3 = fmaf(nv.x, wd.x, h3); h3 = fmaf(nv.y, wd.y, h3);
                h3 = fmaf(nv.z, wd.z, h3); h3 = fmaf(nv.w, wd.w, h3);
            }
            float r = tanhf(h0) * sW2[a0]      + tanhf(h1) * sW2[a0 + 8]
                    + tanhf(h2) * sW2[a0 + 16] + tanhf(h3) * sW2[a0 + 24];
            r += __shfl_xor(r, 1, 64);
            r += __shfl_xor(r, 2, 64);
            r += __shfl_xor(r, 4, 64);
            if (a0 == 0) sSc[w][t8] = r;
            const float4 sc0 = *(const float4*)&sSc[w][0];
            const float4 sc1 = *(const float4*)&sSc[w][4];
            float mx = fmaxf(fmaxf(fmaxf(sc0.x, sc0.y), fmaxf(sc0.z, sc0.w)),
                             fmaxf(fmaxf(sc1.x, sc1.y), fmaxf(sc1.z, sc1.w)));
            const float e0 = __expf(sc0.x - mx), e1 = __expf(sc0.y - mx);
            const float e2 = __expf(sc0.z - mx), e3 = __expf(sc0.w - mx);
            const float e4 = __expf(sc1.x - mx), e5 = __expf(sc1.y - mx);
            const float e6 = __expf(sc1.z - mx), e7 = __expf(sc1.w - mx);
            const float inv = 1.f / (e0 + e1 + e2 + e3 + e4 + e5 + e6 + e7);
            agg[i] = (e0 * acc[0] + e1 * acc[1] + e2 * acc[2] + e3 * acc[3]
                    + e4 * acc[4] + e5 * acc[5] + e6 * acc[6] + e7 * acc[7]) * inv;
        }

        // ---- phase B: fused projection, W element reused by 4 samples ----
        float v[4][8];
        #pragma unroll
        for (int i = 0; i < 4; ++i) {
            if (i < nvalid) {
                const float4* nr = (const float4*)(node_embeddings
                                     + (size_t)nidx[i] * E_DIM + lane * 8);
                const float4 n0 = nr[0], n1 = nr[1];
                v[i][0] = n0.x; v[i][1] = n0.y; v[i][2] = n0.z; v[i][3] = n0.w;
                v[i][4] = n1.x; v[i][5] = n1.y; v[i][6] = n1.z; v[i][7] = n1.w;
            } else {
                #pragma unroll
                for (int k = 0; k < 8; ++k) v[i][k] = 0.f;
            }
        }
        const float* Wp = Wty + lane * 8;
        #pragma unroll 8
        for (int u = 0; u < U_DIM; ++u) {
            const float4 w0 = *(const float4*)(Wp + (size_t)u * E_DIM);
            const float4 w1 = *(const float4*)(Wp + (size_t)u * E_DIM + 4);
            #pragma unroll
            for (int i = 0; i < 4; ++i) {
                const float au = bcast_lane(agg[i], u);
                v[i][0] = fmaf(au, w0.x, v[i][0]); v[i][1] = fmaf(au, w0.y, v[i][1]);
                v[i][2] = fmaf(au, w0.z, v[i][2]); v[i][3] = fmaf(au, w0.w, v[i][3]);
                v[i][4] = fmaf(au, w1.x, v[i][4]); v[i][5] = fmaf(au, w1.y, v[i][5]);
                v[i][6] = fmaf(au, w1.z, v[i][6]); v[i][7] = fmaf(au, w1.w, v[i][7]);
            }
        }
        #pragma unroll
        for (int i = 0; i < 4; ++i) {
            if (i >= nvalid) continue;
            float ss = v[i][0]*v[i][0] + v[i][1]*v[i][1] + v[i][2]*v[i][2] + v[i][3]*v[i][3]
                     + v[i][4]*v[i][4] + v[i][5]*v[i][5] + v[i][6]*v[i][6] + v[i][7]*v[i][7];
            #pragma unroll
            for (int off = 1; off < 64; off <<= 1)
                ss += __shfl_xor(ss, off, 64);
            const float invn = 1.f / fmaxf(sqrtf(ss), 1e-12f);
            float4 o0, o1;
            o0.x = v[i][0]*invn; o0.y = v[i][1]*invn;
            o0.z = v[i][2]*invn; o0.w = v[i][3]*invn;
            o1.x = v[i][4]*invn; o1.y = v[i][5]*invn;
            o1.z = v[i][6]*invn; o1.w = v[i][7]*invn;
            float4* op = (float4*)(out + (size_t)sidx[i] * E_DIM + lane * 8);
            op[0] = o0; op[1] = o1;
        }
    }
}

extern "C" void kernel_launch(void* const* d_in, const int* in_sizes, int n_in,
                              void* d_out, int out_size, void* d_ws, size_t ws_size,
                              hipStream_t stream) {
    const float* node_embeddings      = (const float*)d_in[0];
    const float* node_type_embeddings = (const float*)d_in[1];
    const float* trans_weights        = (const float*)d_in[2];
    const float* trans_weights_s1     = (const float*)d_in[3];
    const float* trans_weights_s2     = (const float*)d_in[4];
    const int*   train_inputs         = (const int*)d_in[5];
    const int*   train_types          = (const int*)d_in[6];
    const int*   node_neigh           = (const int*)d_in[7];
    float* out = (float*)d_out;

    int* cnt = (int*)d_ws;
    int* bkt = (int*)((char*)d_ws + 256);

    hipMemsetAsync(cnt, 0, 32, stream);
    bucket_kernel<<<BATCH / 256, 256, 0, stream>>>(train_types, cnt, bkt);
    gatne_main<<<dim3(T_DIM, 64), 256, 0, stream>>>(
        node_embeddings, node_type_embeddings, trans_weights,
        trans_weights_s1, trans_weights_s2,
        train_inputs, cnt, bkt, node_neigh, out);
}